// Round 1
// baseline (140.617 us; speedup 1.0000x reference)
//
#include <hip/hip_runtime.h>
#include <math.h>

#define B_SZ 256
#define N_SZ 1024
#define D_MODEL 128
#define NUM_CLASSES 32

// exp(-ETA*d^2) = 2^(d^2 * -ETA*log2(e));  -4 * 1.4426950408889634
#define K_EXP (-5.770780163555854f)
// cos(pi*rc/RC) with v_cos (revolutions): arg = rc/(2*RC) = rc/12
#define K_COS (1.0f / 12.0f)

__device__ __forceinline__ void compute_prod(const float4 xv, float& r, int& c, float p[4]) {
    const float y00 = 0.28209479177387814f;  // 0.5/sqrt(pi)
    const float c1  = 0.48860251190291992f;  // sqrt(3/(4pi))
    float r2 = xv.x * xv.x + xv.y * xv.y + xv.z * xv.z;
    r = sqrtf(r2);
    c = (int)xv.w;
    float inv_r = (r > 0.0f) ? __builtin_amdgcn_rcpf(r) : 0.0f;
    float ux = xv.x * inv_r, uy = xv.y * inv_r, uz = xv.z * inv_r;
    float rc = fminf(r, 6.0f);
    float env = 0.5f * __builtin_amdgcn_cosf(rc * K_COS) + 0.5f;
    float d0 = 0.0f - r, d1 = 1.5f - r, d2 = 3.0f - r, d3 = 4.5f - r;
    float rad0 = __builtin_amdgcn_exp2f(d0 * d0 * K_EXP);
    float rad1 = __builtin_amdgcn_exp2f(d1 * d1 * K_EXP);
    float rad2 = __builtin_amdgcn_exp2f(d2 * d2 * K_EXP);
    float rad3 = __builtin_amdgcn_exp2f(d3 * d3 * K_EXP);
    p[0] = y00 * rad0 * env;
    p[1] = c1 * uy * rad1 * env;
    p[2] = c1 * uz * rad2 * env;
    p[3] = c1 * ux * rad3 * env;
}

// One block per batch (1024 threads = 1024 points). Phases:
//  1. per-point prod -> LDS SoA; sum of squares per feature via LDS atomics
//  2. inv_norm[128] in LDS
//  3a. per-point LayerNorm stats computed ONCE per point -> LDS (amb float4, {bneg,cls})
//  3b. 32 lanes per point, lane l writes features [4l,4l+4). Wave = 2 consecutive
//      points -> every global_store_dwordx4 is 1024 B fully contiguous
//      (vs previous 16 x 64 B scattered chunks at 512 B stride).
__global__ __launch_bounds__(1024) void ape_fused_kernel(const float* __restrict__ x,
                                                         float* __restrict__ out) {
    __shared__ float nsq[D_MODEL];
    __shared__ float invn[D_MODEL];
    __shared__ float sp0[N_SZ], sp1[N_SZ], sp2[N_SZ], sp3[N_SZ];
    __shared__ int   scls[N_SZ];
    __shared__ float4 samb[N_SZ];   // per-point normalized values (a - mean)/std at the 4 hot features
    __shared__ float2 sbc[N_SZ];    // per-point {bneg, cls-as-bits}

    const int b = blockIdx.x;
    const int t = threadIdx.x;
    if (t < D_MODEL) nsq[t] = 0.0f;
    __syncthreads();

    // Phase 1: one point per thread
    {
        float4 xv = ((const float4*)x)[(size_t)b * N_SZ + t];
        float r; int c; float p[4];
        compute_prod(xv, r, c, p);
        if (r <= 0.0f) { p[0] = p[1] = p[2] = p[3] = 0.0f; }
        sp0[t] = p[0]; sp1[t] = p[1]; sp2[t] = p[2]; sp3[t] = p[3];
        scls[t] = c;
        if (r > 0.0f) {
            atomicAdd(&nsq[0 * NUM_CLASSES + c], p[0] * p[0]);
            atomicAdd(&nsq[1 * NUM_CLASSES + c], p[1] * p[1]);
            atomicAdd(&nsq[2 * NUM_CLASSES + c], p[2] * p[2]);
            atomicAdd(&nsq[3 * NUM_CLASSES + c], p[3] * p[3]);
        }
    }
    __syncthreads();

    // Phase 2: inv_norm per feature
    if (t < D_MODEL) {
        invn[t] = __builtin_amdgcn_rcpf(fmaxf(sqrtf(nsq[t]), 1e-12f));
    }
    __syncthreads();

    // Phase 3a: LayerNorm stats, once per point (thread t owns point t)
    {
        const int c = scls[t];
        float pn0 = sp0[t] * invn[0 * NUM_CLASSES + c];
        float pn1 = sp1[t] * invn[1 * NUM_CLASSES + c];
        float pn2 = sp2[t] * invn[2 * NUM_CLASSES + c];
        float pn3 = sp3[t] * invn[3 * NUM_CLASSES + c];
        float sum = pn0 + pn1 + pn2 + pn3;
        float mean = sum * (1.0f / 128.0f);
        float sumsq = pn0 * pn0 + pn1 * pn1 + pn2 * pn2 + pn3 * pn3;
        float var = fmaxf((sumsq - 128.0f * mean * mean) * (1.0f / 127.0f), 0.0f);
        float inv_std = __builtin_amdgcn_rcpf(sqrtf(var) + 1e-6f);
        float bneg = -mean * inv_std;
        samb[t] = make_float4(pn0 * inv_std + bneg,
                              pn1 * inv_std + bneg,
                              pn2 * inv_std + bneg,
                              pn3 * inv_std + bneg);
        sbc[t] = make_float2(bneg, __int_as_float(c));
    }
    __syncthreads();

    // Phase 3b: 32 lanes per point; each wave stores 1024 contiguous bytes.
    {
        const int lane = t & 31;        // feature-chunk owner within point
        const int grp  = t >> 5;        // 0..31: point offset within each pass-stripe
        const int qsel = lane >> 3;     // which radial block's amb this lane may need
        const int m    = (lane & 7) * 4; // feature offset within the 32-class block
        const float* samb_f = (const float*)samb;
        float4* op = (float4*)out + ((size_t)b * N_SZ + grp) * 32 + lane;
#pragma unroll
        for (int k = 0; k < 32; ++k) {
            const int n = (k << 5) + grp;
            const float a  = samb_f[(n << 2) + qsel];
            const float2 bc = sbc[n];
            const float bneg = bc.x;
            const int   c    = __float_as_int(bc.y);
            float4 o;
            o.x = (c == m + 0) ? a : bneg;
            o.y = (c == m + 1) ? a : bneg;
            o.z = (c == m + 2) ? a : bneg;
            o.w = (c == m + 3) ? a : bneg;
            op[k * (32 * 32)] = o;
        }
    }
}

extern "C" void kernel_launch(void* const* d_in, const int* in_sizes, int n_in,
                              void* d_out, int out_size, void* d_ws, size_t ws_size,
                              hipStream_t stream) {
    const float* x = (const float*)d_in[0];
    float* out = (float*)d_out;
    ape_fused_kernel<<<B_SZ, 1024, 0, stream>>>(x, out);
}